// Round 12
// baseline (170.914 us; speedup 1.0000x reference)
//
#include <hip/hip_runtime.h>
#include <math.h>

// MinkowskiInstanceNorm: segment instance-norm, N x C=32, S<=64 segments (sorted seg_ids).
// ws (floats): SHARDS @0: 8 x 4160 (sum[2048], sq[2048], cnt[64]) = 33280
//              SCALE @33280 (2048), SHIFT @35328 (2048)

#define NSH      8
#define SHARD_F  4160
#define WS_SCALE (NSH * SHARD_F)
#define WS_SHIFT (WS_SCALE + 2048)

#define NB    8      // DMA pipeline depth per wave (1KB slots)
#define STEPS 128    // 128 x 1KB = 128KB per wave = 8192 float4 = 1024 rows

typedef float f32x4 __attribute__((ext_vector_type(4)));

typedef const __attribute__((address_space(1))) unsigned int ga_u32;
typedef __attribute__((address_space(3))) unsigned int la_u32;
#define GLL16(gp, lp) \
    __builtin_amdgcn_global_load_lds((ga_u32*)(gp), (la_u32*)(lp), 16, 0, 0)

__global__ __launch_bounds__(256) void zero_ws_kernel(float* __restrict__ ws) {
    int t = blockIdx.x * blockDim.x + threadIdx.x;
    if (t < NSH * SHARD_F) ws[t] = 0.0f;
}

__device__ inline int lower_bound(const int* __restrict__ a, int n, int key) {
    int lo = 0, hi = n;
    while (lo < hi) {
        int mid = (lo + hi) >> 1;
        if (a[mid] < key) lo = mid + 1; else hi = mid;
    }
    return lo;
}

// Per-wave async-DMA reduce. Wave g = blockIdx*4+wid owns float4 [g*8192,(g+1)*8192).
// Single-segment waves (all but ~8): counted-vmcnt DMA pipeline -> shfl reduce ->
// 65 global atomics per 128KB. No LDS bins, no block barrier.
__global__ __launch_bounds__(256) void reduce_kernel(
        const float* __restrict__ feats, const int* __restrict__ seg,
        float* __restrict__ ws, int total4, int N) {
    __shared__ __align__(16) char dma[4 * NB * 1024];   // 32 KB: 4 waves x 8 slots
    int t    = threadIdx.x;
    int wid  = t >> 6;
    int lane = t & 63;
    const f32x4* f4 = (const f32x4*)feats;

    long gw    = (long)blockIdx.x * 4 + wid;
    long ebase = gw * (STEPS * 64);
    if (ebase >= total4) return;
    long eend = ebase + STEPS * 64;
    if (eend > total4) eend = total4;
    int sA = seg[(int)(ebase >> 3)];
    int sB = seg[(int)((eend - 1) >> 3)];
    float* shard = ws + ((int)gw & (NSH - 1)) * SHARD_F;

    if (sA == sB && (eend - ebase) == STEPS * 64) {
        // ---- fast path ----
        f32x4 acc  = {0.f, 0.f, 0.f, 0.f};
        f32x4 accq = {0.f, 0.f, 0.f, 0.f};
        const char* g = (const char*)(f4 + ebase) + lane * 16;
        char* lb = &dma[wid * (NB * 1024)];
        asm volatile("s_waitcnt vmcnt(0)" ::: "memory");   // exact counting
        #pragma unroll
        for (int k = 0; k < NB; ++k)
            GLL16(g + k * 1024, lb + k * 1024);
        for (int k = 0; k < STEPS - NB; ++k) {
            asm volatile("s_waitcnt vmcnt(7)" ::: "memory");   // oldest landed
            __builtin_amdgcn_sched_barrier(0);
            f32x4 v = *(const f32x4*)(lb + (k & (NB - 1)) * 1024 + lane * 16);
            acc  += v;
            accq += v * v;
            __builtin_amdgcn_sched_barrier(0);
            GLL16(g + (k + NB) * 1024, lb + (k & (NB - 1)) * 1024);
        }
        asm volatile("s_waitcnt vmcnt(0)" ::: "memory");
        __builtin_amdgcn_sched_barrier(0);
        #pragma unroll
        for (int k = STEPS - NB; k < STEPS; ++k) {
            f32x4 v = *(const f32x4*)(lb + (k & (NB - 1)) * 1024 + lane * 16);
            acc  += v;
            accq += v * v;
        }
        // combine lanes sharing channel-group (stride-64 walk keeps cg = lane&7)
        #pragma unroll
        for (int m = 8; m <= 32; m <<= 1) {
            acc.x  += __shfl_xor(acc.x, m);  acc.y  += __shfl_xor(acc.y, m);
            acc.z  += __shfl_xor(acc.z, m);  acc.w  += __shfl_xor(acc.w, m);
            accq.x += __shfl_xor(accq.x, m); accq.y += __shfl_xor(accq.y, m);
            accq.z += __shfl_xor(accq.z, m); accq.w += __shfl_xor(accq.w, m);
        }
        if (lane < 8) {
            int bse = sA * 32 + lane * 4;
            atomicAdd(&shard[bse + 0], acc.x);
            atomicAdd(&shard[bse + 1], acc.y);
            atomicAdd(&shard[bse + 2], acc.z);
            atomicAdd(&shard[bse + 3], acc.w);
            atomicAdd(&shard[2048 + bse + 0], accq.x);
            atomicAdd(&shard[2048 + bse + 1], accq.y);
            atomicAdd(&shard[2048 + bse + 2], accq.z);
            atomicAdd(&shard[2048 + bse + 3], accq.w);
        }
        if (lane == 0) atomicAdd(&shard[4096 + sA], (float)(STEPS * 64 / 8));
    } else {
        // ---- boundary/tail waves (<=8 in grid): per-segment uniform sub-loops ----
        for (int s = sA; s <= sB; ++s) {
            long lo = (s == sA) ? ebase : (long)lower_bound(seg, N, s) * 8;
            long hi = (s == sB) ? eend  : (long)lower_bound(seg, N, s + 1) * 8;
            if (hi <= lo) continue;
            f32x4 acc  = {0.f, 0.f, 0.f, 0.f};
            f32x4 accq = {0.f, 0.f, 0.f, 0.f};
            float rcnt = 0.0f;
            int cg_s = (int)((lo + lane) & 7);
            for (long e = lo + lane; e < hi; e += 64) {
                f32x4 v = f4[e];
                acc  += v;
                accq += v * v;
                rcnt += (cg_s == 0) ? 1.0f : 0.0f;
            }
            int bse = s * 32 + cg_s * 4;
            atomicAdd(&shard[bse + 0], acc.x);
            atomicAdd(&shard[bse + 1], acc.y);
            atomicAdd(&shard[bse + 2], acc.z);
            atomicAdd(&shard[bse + 3], acc.w);
            atomicAdd(&shard[2048 + bse + 0], accq.x);
            atomicAdd(&shard[2048 + bse + 1], accq.y);
            atomicAdd(&shard[2048 + bse + 2], accq.z);
            atomicAdd(&shard[2048 + bse + 3], accq.w);
            if (rcnt != 0.0f) atomicAdd(&shard[4096 + s], rcnt);
        }
    }
}

__global__ void stats_kernel(const float* __restrict__ w,
                             const float* __restrict__ b,
                             const int* __restrict__ nsp,
                             float* __restrict__ ws) {
    int t  = threadIdx.x;
    int ns = min(*nsp, 64);
    for (int o = t; o < ns * 32; o += 256) {
        int s = o >> 5, c = o & 31;
        float S = 0.f, Q = 0.f, C = 0.f;
        #pragma unroll
        for (int sh = 0; sh < NSH; ++sh) {
            const float* base = ws + sh * SHARD_F;
            S += base[o];
            Q += base[2048 + o];
            C += base[4096 + s];
        }
        float cnt  = fmaxf(C, 1.0f);
        float mean = S / cnt;
        float var  = fmaxf(Q / cnt - mean * mean, 0.0f);
        float inv  = rsqrtf(var + 1e-8f);
        float sc   = inv * w[c];
        ws[WS_SCALE + o] = sc;
        ws[WS_SHIFT + o] = b[c] - mean * sc;
    }
}

// Proven R10 apply: grid-stride, plain load (keep feats L3-hot), NT store.
__global__ __launch_bounds__(256) void apply_kernel(
        const float* __restrict__ feats, const int* __restrict__ seg,
        const float* __restrict__ ws, float* __restrict__ out, int total4) {
    const f32x4* f4 = (const f32x4*)feats;
    f32x4*       o4 = (f32x4*)out;
    const f32x4* scale4 = (const f32x4*)(ws + WS_SCALE);
    const f32x4* shift4 = (const f32x4*)(ws + WS_SHIFT);
    int stride = gridDim.x * blockDim.x;
    for (int i = blockIdx.x * blockDim.x + threadIdx.x; i < total4; i += stride) {
        int row = i >> 3, cg = i & 7;
        int s = seg[row];
        f32x4 v  = f4[i];
        f32x4 sc = scale4[s * 8 + cg];
        f32x4 sh = shift4[s * 8 + cg];
        f32x4 o;
        o.x = fmaf(v.x, sc.x, sh.x); o.y = fmaf(v.y, sc.y, sh.y);
        o.z = fmaf(v.z, sc.z, sh.z); o.w = fmaf(v.w, sc.w, sh.w);
        __builtin_nontemporal_store(o, &o4[i]);
    }
}

extern "C" void kernel_launch(void* const* d_in, const int* in_sizes, int n_in,
                              void* d_out, int out_size, void* d_ws, size_t ws_size,
                              hipStream_t stream) {
    const float* feats = (const float*)d_in[0];
    const int*   seg   = (const int*)d_in[1];
    const float* w     = (const float*)d_in[2];
    const float* b     = (const float*)d_in[3];
    const int*   nsp   = (const int*)d_in[4];
    float* out = (float*)d_out;
    float* ws  = (float*)d_ws;

    int N = in_sizes[1];
    int total4 = N * 8;
    int nwaves = (total4 + STEPS * 64 - 1) / (STEPS * 64);
    int nblk_r = (nwaves + 3) / 4;

    hipLaunchKernelGGL(zero_ws_kernel, dim3((NSH * SHARD_F + 255) / 256), dim3(256),
                       0, stream, ws);
    hipLaunchKernelGGL(reduce_kernel, dim3(nblk_r), dim3(256), 0, stream,
                       feats, seg, ws, total4, N);
    hipLaunchKernelGGL(stats_kernel, dim3(1), dim3(256), 0, stream,
                       w, b, nsp, ws);
    hipLaunchKernelGGL(apply_kernel, dim3(4096), dim3(256), 0, stream,
                       feats, seg, ws, out, total4);
}